// Round 6
// baseline (143.786 us; speedup 1.0000x reference)
//
#include <hip/hip_runtime.h>
#include <hip/hip_bf16.h>
#include <math.h>

// Problem constants (B, Cin, Cmid, H, W) = (2, 256, 128, 112, 112), R=3
constexpr int B    = 2;
constexpr int CIN  = 256;
constexpr int CMID = 128;
constexpr int H    = 112;
constexpr int W    = 112;
constexpr int HW   = H * W;        // 12544
constexpr int NPIX = B * HW;       // 25088
constexpr int RAD  = 3;
constexpr int KS   = 7;
constexpr int DD   = 49;

typedef __attribute__((ext_vector_type(8))) short  short8;   // 8 bf16 (4 VGPR)
typedef __attribute__((ext_vector_type(4))) float  float4v;  // MFMA C/D

// hardware v_cvt_pk_bf16_f32 (RNE) via HIP intrinsic
__device__ __forceinline__ unsigned pkbf(float a, float b) {
    union { __hip_bfloat162 h; unsigned u; } c;
    c.h = __float22bfloat162_rn(make_float2(a, b));
    return c.u;
}

// ---------------------------------------------------------------------------
// Kernel 0: convert Wq, Wk fp32 -> bf16, and build pair-transposed Wv:
//   wv2[e2*49 + d] = { Wv[d][2*e2], Wv[d][2*e2+1] (or 0 pad) }
// so corr's lane d reads its Wv row via 25 COALESCED float2 loads instead of
// 49 scattered scalar gathers (stride-196B rows splinter ~20+ segments/inst).
// ---------------------------------------------------------------------------
__global__ __launch_bounds__(256) void convert_w(
    const float* __restrict__ Wq, const float* __restrict__ Wk,
    const float* __restrict__ Wvm,
    unsigned short* __restrict__ wqb, unsigned short* __restrict__ wkb,
    float2* __restrict__ wv2)
{
    const int i  = blockIdx.x * 256 + threadIdx.x;
    const int n4 = (CMID * CIN) / 4;                 // 8192 per matrix
    if (i < 2 * n4) {
        const float4 v = (i < n4) ? ((const float4*)Wq)[i] : ((const float4*)Wk)[i - n4];
        uint2 r;
        r.x = pkbf(v.x, v.y);
        r.y = pkbf(v.z, v.w);
        if (i < n4) ((uint2*)wqb)[i] = r;
        else        ((uint2*)wkb)[i - n4] = r;
    } else {
        const int j = i - 2 * n4;
        if (j < 25 * DD) {
            const int e2 = j / DD, d = j % DD;
            const float a  = Wvm[d * DD + 2 * e2];
            const float bb = (2 * e2 + 1 < DD) ? Wvm[d * DD + 2 * e2 + 1] : 0.f;
            wv2[j] = make_float2(a, bb);
        }
    }
}

// ---------------------------------------------------------------------------
// Kernel 1: q = l2norm(Wq @ phi_cur), k = l2norm(Wk @ phi_rnd)  via bf16 MFMA.
// Block = 64 pixels, all 128 outputs.  phi tile staged in LDS with COALESCED
// float4 channel-row loads, transposed during write (hw-packed bf16 ch-pairs,
// b32 writes) into pixel-major rows, stride 264 shorts (528 B; holds all 256
// channels; 132 dwords = 4 mod 32 -> frag ds_read_b128 ~2-way = free, m136).
// Wave w owns out-channels [32w,32w+32): A-frags preloaded into registers;
// K-loop = 8 x (4 B-frag ds_reads + 8 MFMA).  Cross-wave l2norm via LDS.
// ---------------------------------------------------------------------------
constexpr int PSTR = 264;           // shorts per pixel row in pt

__global__ __launch_bounds__(256) void proj_mfma(
    const float* __restrict__ phi_cur, const float* __restrict__ phi_rnd,
    const unsigned short* __restrict__ wq_bf, const unsigned short* __restrict__ wk_bf,
    unsigned short* __restrict__ q_ws, unsigned short* __restrict__ k_ws)
{
    __shared__ unsigned short pt[64 * PSTR];  // 33,792 B  pixel-major bf16
    __shared__ float red[4][64];

    const int tid  = threadIdx.x;
    const int lane = tid & 63;
    const int wv   = __builtin_amdgcn_readfirstlane(tid >> 6);
    const int t    = blockIdx.y;                    // 0 -> q, 1 -> k

    const float* __restrict__ phi          = t ? phi_rnd : phi_cur;
    const unsigned short* __restrict__ Wbf = t ? wk_bf : wq_bf;
    unsigned short* __restrict__ outp      = t ? k_ws : q_ws;

    const int pgb = blockIdx.x * 64;                // 64-aligned, no b crossing
    const int b   = pgb / HW;
    const int pim = pgb % HW;
    const float* pbase = phi + (size_t)b * CIN * HW + pim;

    // ---- stage phi tile: 8 passes; thread -> (channel-pair, pixel-quad) ----
#pragma unroll
    for (int pass = 0; pass < 8; ++pass) {
        const int idx = pass * 256 + tid;
        const int cp  = idx >> 4;          // channel pair 0..127
        const int pq  = idx & 15;          // pixel quad  0..15
        const int c0  = cp * 2;
        const float4 va = *(const float4*)(pbase + (size_t)c0 * HW + pq * 4);
        const float4 vb = *(const float4*)(pbase + (size_t)(c0 + 1) * HW + pq * 4);
        *(unsigned*)(pt + (pq * 4 + 0) * PSTR + c0) = pkbf(va.x, vb.x);
        *(unsigned*)(pt + (pq * 4 + 1) * PSTR + c0) = pkbf(va.y, vb.y);
        *(unsigned*)(pt + (pq * 4 + 2) * PSTR + c0) = pkbf(va.z, vb.z);
        *(unsigned*)(pt + (pq * 4 + 3) * PSTR + c0) = pkbf(va.w, vb.w);
    }

    // ---- A-frags: this wave's 32 W rows, held in registers (L2-hot) ----
    const int m = lane & 15, quad = lane >> 4;
    short8 af[2][8];
#pragma unroll
    for (int ot = 0; ot < 2; ++ot)
#pragma unroll
        for (int kc = 0; kc < 8; ++kc)
            af[ot][kc] = *(const short8*)(Wbf +
                (size_t)(wv * 32 + ot * 16 + m) * CIN + kc * 32 + quad * 8);

    __syncthreads();

    // ---- MFMA: 2 out-tiles x 4 pixel-tiles x K=256 ----
    float4v acc[2][4];
#pragma unroll
    for (int ot = 0; ot < 2; ++ot)
#pragma unroll
        for (int nt = 0; nt < 4; ++nt) acc[ot][nt] = (float4v)0.f;

#pragma unroll
    for (int kc = 0; kc < 8; ++kc) {
        short8 bf[4];
#pragma unroll
        for (int nt = 0; nt < 4; ++nt)
            bf[nt] = *(const short8*)(pt + (nt * 16 + m) * PSTR + kc * 32 + quad * 8);
#pragma unroll
        for (int ot = 0; ot < 2; ++ot)
#pragma unroll
            for (int nt = 0; nt < 4; ++nt)
                acc[ot][nt] = __builtin_amdgcn_mfma_f32_16x16x32_bf16(
                    af[ot][kc], bf[nt], acc[ot][nt], 0, 0, 0);
    }

    // ---- per-pixel L2 norm: C layout col=lane&15=pixel, row=quad*4+reg=och
#pragma unroll
    for (int nt = 0; nt < 4; ++nt) {
        float ss = 0.f;
#pragma unroll
        for (int ot = 0; ot < 2; ++ot)
#pragma unroll
            for (int r = 0; r < 4; ++r)
                ss = fmaf(acc[ot][nt][r], acc[ot][nt][r], ss);
        ss += __shfl_xor(ss, 16, 64);
        ss += __shfl_xor(ss, 32, 64);
        if (quad == 0) red[wv][nt * 16 + m] = ss;
    }
    __syncthreads();

    float inv[4];
#pragma unroll
    for (int nt = 0; nt < 4; ++nt) {
        const int px = nt * 16 + m;
        const float tot = red[0][px] + red[1][px] + red[2][px] + red[3][px];
        inv[nt] = 1.f / fmaxf(sqrtf(tot), 1e-12f);
    }

    // ---- store bf16 pixel-major ----
#pragma unroll
    for (int nt = 0; nt < 4; ++nt)
#pragma unroll
        for (int ot = 0; ot < 2; ++ot) {
            uint2 st;
            st.x = pkbf(acc[ot][nt][0] * inv[nt], acc[ot][nt][1] * inv[nt]);
            st.y = pkbf(acc[ot][nt][2] * inv[nt], acc[ot][nt][3] * inv[nt]);
            *(uint2*)(outp + (size_t)(pgb + nt * 16 + m) * CMID
                      + wv * 32 + ot * 16 + quad * 4) = st;
        }
}

// ---------------------------------------------------------------------------
// Kernel 2: correlation via MFMA band-GEMM + Wv + geometry + softmax.
// Block = 16 pixels of one row.  Phase A: stage k-tile (7x22 vectors, bf16,
// stride 136 shorts), q-tile, AND the 7x22x3 P_rnd tile (zeros OOB) in LDS;
// Wv row loaded per-lane from the pair-transposed wv2 (25 coalesced float2).
// Phase B: 14 (row r, n-tile) groups round-robin over 4 waves: 4 chained
// 16x16x32 MFMA; band-extract D[p][cc], off = cc-p in [0,6] -> cs[p][r*7+off].
// Phase C (lane = offset d): geometry from LDS prt, logits, softmax, moments.
// ---------------------------------------------------------------------------
constexpr int TILE = 16;
constexpr int COLS = TILE + 6;      // 22
constexpr int NV   = KS * COLS;     // 154 staged pixel-vectors
constexpr int KSTR = 136;           // shorts per vector in LDS (272 B)

__global__ __launch_bounds__(256) void corr_kernel(
    const unsigned short* __restrict__ q_ws, const unsigned short* __restrict__ k_ws,
    const float* __restrict__ P_cur, const float* __restrict__ P_rnd,
    const float2* __restrict__ wv2, const float* __restrict__ bv,
    const float* __restrict__ gamma_p, float* __restrict__ out)
{
    __shared__ unsigned short kt[NV * KSTR];     // 41,888 B
    __shared__ unsigned short qt[TILE * KSTR];   //  4,352 B
    __shared__ float cs[TILE][52];               //  3,328 B corr vectors
    __shared__ float prt[3 * NV];                //  1,848 B P_rnd tile

    const int tid  = threadIdx.x;
    const int lane = tid & 63;
    const int wv   = __builtin_amdgcn_readfirstlane(tid >> 6);
    const int w0   = blockIdx.x * TILE;
    const int h    = blockIdx.y;
    const int b    = blockIdx.z;

    // ---- phase A: stage k-tile + q-tile (coalesced dwordx4; OOB zeros) ----
    const int sub  = tid & 15;
    const int vgrp = tid >> 4;          // 0..15
#pragma unroll
    for (int pass = 0; pass < 10; ++pass) {
        const int vi = pass * 16 + vgrp;
        if (vi < NV) {
            const int rr = vi / COLS;
            const int cc = vi % COLS;
            const int hh = h + rr - RAD;
            const int ww = w0 + cc - RAD;
            uint4 v = make_uint4(0, 0, 0, 0);
            if (hh >= 0 && hh < H && ww >= 0 && ww < W)
                v = *(const uint4*)(k_ws + (size_t)(b * HW + hh * W + ww) * CMID + sub * 8);
            *(uint4*)(kt + vi * KSTR + sub * 8) = v;
        }
    }
    {
        const uint4 v = *(const uint4*)(q_ws + (size_t)(b * HW + h * W + w0 + vgrp) * CMID + sub * 8);
        *(uint4*)(qt + vgrp * KSTR + sub * 8) = v;
    }
    // ---- stage P_rnd tile (3 ch x 154 slots; zeros OOB -> matches padding,
    // and also removes the per-lane inb branch in phase C) ----
#pragma unroll
    for (int pass = 0; pass < 2; ++pass) {
        const int idx = pass * 256 + tid;
        if (idx < 3 * NV) {
            const int ch = idx / NV;
            const int vi = idx % NV;
            const int rr = vi / COLS;
            const int cc = vi % COLS;
            const int hh = h + rr - RAD;
            const int ww = w0 + cc - RAD;
            float v = 0.f;
            if (hh >= 0 && hh < H && ww >= 0 && ww < W)
                v = P_rnd[((size_t)b * 3 + ch) * HW + hh * W + ww];
            prt[idx] = v;
        }
    }

    // ---- per-lane constants for phase C (coalesced; overlap staging) ----
    const int  ld    = (lane < DD) ? lane : 0;
    const bool valid = (lane < DD);
    float wrow[52];
#pragma unroll
    for (int e2 = 0; e2 < 25; ++e2) {
        const float2 v = wv2[e2 * DD + ld];   // lanes d consecutive -> coalesced
        wrow[2 * e2]     = v.x;
        wrow[2 * e2 + 1] = v.y;               // wrow[49] = 0 pad from convert_w
    }
    wrow[50] = wrow[51] = 0.f;
    const float bvv   = bv[ld];
    const float gamma = gamma_p[0];

    __syncthreads();

    // zero the cs padding (cols 49..51) so phase C's 0*pad stays 0
    if (tid < TILE * 3)
        cs[tid / 3][49 + tid % 3] = 0.f;

    // ---- phase B: MFMA band-GEMM ----
    const int m = lane & 15, quad = lane >> 4;
    for (int g = wv; g < 14; g += 4) {
        const int r  = g >> 1;
        const int nt = g & 1;
        const int vi = min(r * COLS + nt * 16 + m, NV - 1);  // clamp OOB cols
        float4v acc = (float4v)0.f;
#pragma unroll
        for (int kc = 0; kc < 4; ++kc) {
            const short8 afrag = *(const short8*)(qt + m * KSTR + kc * 32 + quad * 8);
            const short8 bfrag = *(const short8*)(kt + vi * KSTR + kc * 32 + quad * 8);
            acc = __builtin_amdgcn_mfma_f32_16x16x32_bf16(afrag, bfrag, acc, 0, 0, 0);
        }
        // band extract: D row = pixel = quad*4+reg, col cc = nt*16 + m
#pragma unroll
        for (int reg = 0; reg < 4; ++reg) {
            const int p   = quad * 4 + reg;
            const int off = nt * 16 + m - p;     // dx + RAD
            if (off >= 0 && off <= 6)
                cs[p][r * 7 + off] = acc[reg];
        }
    }
    __syncthreads();

    // ---- phase C: geometry + logits + softmax + moments (lane = d) ----
    const int dyr = ld / KS;
    const int dxc = ld % KS;
    const int dy  = dyr - RAD;
    const int dx  = dxc - RAD;

    for (int i = 0; i < 4; ++i) {
        const int pl = wv * 4 + i;      // pixel local 0..15
        const int pg = b * HW + h * W + w0 + pl;

        // geometry: neighbor from LDS tile (zeros OOB = reference padding)
        const int vi = dyr * COLS + pl + dxc;
        const float rx = prt[vi];
        const float ry = prt[NV + vi];
        const float rz = prt[2 * NV + vi];
        const float* pc = P_cur + (size_t)b * 3 * HW + (h * W + w0 + pl);
        const float cx = pc[0], cy = pc[HW], cz = pc[2 * HW];   // uniform
        const float dpx = cx - rx, dpy = cy - ry, dpz = cz - rz;
        const float dist = sqrtf(fmaxf(dpx * dpx + dpy * dpy + dpz * dpz, 1e-12f));

        float logit = -INFINITY;
        if (valid) {
            float v = bvv;
#pragma unroll
            for (int e4 = 0; e4 < 13; ++e4) {
                const float4 c4 = *(const float4*)&cs[pl][e4 * 4];  // broadcast
                v = fmaf(wrow[e4 * 4 + 0], c4.x, v);
                v = fmaf(wrow[e4 * 4 + 1], c4.y, v);
                v = fmaf(wrow[e4 * 4 + 2], c4.z, v);
                v = fmaf(wrow[e4 * 4 + 3], c4.w, v);
            }
            logit = v + gamma * (-dist - 0.5f * fabsf(dpz));
        }

        float lmax = logit;
#pragma unroll
        for (int off = 32; off; off >>= 1)
            lmax = fmaxf(lmax, __shfl_xor(lmax, off, 64));
        const float e1 = valid ? __expf(logit - lmax) : 0.f;
        float Z = e1;
#pragma unroll
        for (int off = 32; off; off >>= 1)
            Z += __shfl_xor(Z, off, 64);
        const float wgt = e1 / Z;

        float dus = wgt * (float)dx;
        float dvs = wgt * (float)dy;
#pragma unroll
        for (int off = 32; off; off >>= 1) {
            dus += __shfl_xor(dus, off, 64);
            dvs += __shfl_xor(dvs, off, 64);
        }

        if (lane == 0) {
            out[pg]            = dus;
            out[NPIX + pg]     = dvs;
            out[2 * NPIX + pg] = 1.f / Z;   // conf = max w
        }
    }
}

// ---------------------------------------------------------------------------
extern "C" void kernel_launch(void* const* d_in, const int* in_sizes, int n_in,
                              void* d_out, int out_size, void* d_ws, size_t ws_size,
                              hipStream_t stream)
{
    const float* phi_cur = (const float*)d_in[0];
    const float* phi_rnd = (const float*)d_in[1];
    const float* P_cur   = (const float*)d_in[2];
    const float* P_rnd   = (const float*)d_in[3];
    const float* Wq      = (const float*)d_in[4];
    const float* Wk      = (const float*)d_in[5];
    const float* Wv      = (const float*)d_in[6];
    const float* bv      = (const float*)d_in[7];
    const float* gm      = (const float*)d_in[8];
    float* out = (float*)d_out;

    unsigned short* ws   = (unsigned short*)d_ws;
    unsigned short* q_ws = ws;                                  // NPIX*CMID bf16
    unsigned short* k_ws = q_ws + (size_t)NPIX * CMID;          // NPIX*CMID bf16
    unsigned short* wqb  = k_ws + (size_t)NPIX * CMID;          // CMID*CIN bf16
    unsigned short* wkb  = wqb + (size_t)CMID * CIN;
    float2* wv2 = (float2*)(wkb + (size_t)CMID * CIN);          // 25*49 float2
                                                                 // (offset 8B-aligned)

    convert_w<<<dim3((2 * CMID * CIN / 4 + 25 * DD + 255) / 256), 256, 0, stream>>>(
        Wq, Wk, Wv, wqb, wkb, wv2);

    proj_mfma<<<dim3(NPIX / 64, 2), 256, 0, stream>>>(
        phi_cur, phi_rnd, wqb, wkb, q_ws, k_ws);

    corr_kernel<<<dim3(W / TILE, H, B), 256, 0, stream>>>(
        q_ws, k_ws, P_cur, P_rnd, wv2, bv, gm, out);
}